// Round 1
// baseline (327.954 us; speedup 1.0000x reference)
//
#include <hip/hip_runtime.h>
#include <hip/hip_bf16.h>

typedef __bf16 bf16_t;
typedef __bf16 bf16x8 __attribute__((ext_vector_type(8)));
typedef float f32x4 __attribute__((ext_vector_type(4)));

#define E_DIM 1024
#define SEQ   2048
#define NBATCH 4

// ---------------- cast f32 -> bf16 (vectorized, 8 elems/thread) ----------------
__global__ __launch_bounds__(256) void k_cast(const float* __restrict__ src,
                                              bf16_t* __restrict__ dst) {
  const int i = (blockIdx.x * 256 + threadIdx.x) * 8;
  const float4 a = *(const float4*)(src + i);
  const float4 b = *(const float4*)(src + i + 4);
  bf16x8 o;
  o[0] = (bf16_t)a.x; o[1] = (bf16_t)a.y; o[2] = (bf16_t)a.z; o[3] = (bf16_t)a.w;
  o[4] = (bf16_t)b.x; o[5] = (bf16_t)b.y; o[6] = (bf16_t)b.z; o[7] = (bf16_t)b.w;
  *(bf16x8*)(dst + i) = o;
}

// ---------------- GEMM: C = scale * (A @ B^T) + bias (+residual) ----------------
// A: [M][K] bf16 row-major (lda), B: [N][K] bf16 row-major (ldb)  -- both K-contiguous.
// OUTMODE 0: f32 out, 1: bf16 out, 2: bf16 transposed out (writes Vt[b][col][s], SEQ rows/batch)
// 128x128 tile, BK=64, 256 threads = 4 waves (2x2 of 64x64), mfma_f32_16x16x32_bf16.
template <int OUTMODE>
__global__ __launch_bounds__(256) void k_gemm(
    const bf16_t* __restrict__ A, int lda, long sA,
    const bf16_t* __restrict__ B, int ldb, long sB,
    void* __restrict__ Cv, int ldc, long sC,
    int K, float scale,
    const float* __restrict__ bias,
    const float* __restrict__ residual) {
  __shared__ __align__(16) bf16_t As[128 * 64];
  __shared__ __align__(16) bf16_t Bs[128 * 64];
  const int tid = threadIdx.x;
  const int lane = tid & 63;
  const int wid = tid >> 6;
  const int wm = wid >> 1, wn = wid & 1;
  const long bz = blockIdx.z;
  const bf16_t* Ab = A + bz * sA;
  const bf16_t* Bb = B + bz * sB;
  const int brow = blockIdx.x * 128;
  const int bcol = blockIdx.y * 128;

  f32x4 acc[4][4] = {};

  auto stage = [&](int kt) {
#pragma unroll
    for (int c = 0; c < 4; ++c) {
      const int base = c * 4096 + wid * 1024;  // wave-uniform LDS byte base
      const int off = base + lane * 16;        // per-lane byte within tile
      const int row = off >> 7;                // 128 B per row (64 bf16)
      const int cb = (off & 127) >> 1;         // element col within K-tile
      __builtin_amdgcn_global_load_lds(
          (const __attribute__((address_space(1))) void*)(Ab + (long)(brow + row) * lda + kt + cb),
          (__attribute__((address_space(3))) void*)((char*)As + base), 16, 0, 0);
      __builtin_amdgcn_global_load_lds(
          (const __attribute__((address_space(1))) void*)(Bb + (long)(bcol + row) * ldb + kt + cb),
          (__attribute__((address_space(3))) void*)((char*)Bs + base), 16, 0, 0);
    }
  };

  stage(0);
  for (int kt = 0; kt < K; kt += 64) {
    __syncthreads();  // staging complete (compiler drains vmcnt before barrier)
#pragma unroll
    for (int kk = 0; kk < 2; ++kk) {
      const int kb = kk * 32 + ((lane >> 4) << 3);
      bf16x8 af[4], bfr[4];
#pragma unroll
      for (int m = 0; m < 4; ++m)
        af[m] = *(const bf16x8*)&As[(wm * 64 + m * 16 + (lane & 15)) * 64 + kb];
#pragma unroll
      for (int n = 0; n < 4; ++n)
        bfr[n] = *(const bf16x8*)&Bs[(wn * 64 + n * 16 + (lane & 15)) * 64 + kb];
#pragma unroll
      for (int m = 0; m < 4; ++m)
#pragma unroll
        for (int n = 0; n < 4; ++n)
          acc[m][n] = __builtin_amdgcn_mfma_f32_16x16x32_bf16(af[m], bfr[n], acc[m][n], 0, 0, 0);
    }
    __syncthreads();  // all waves done reading LDS
    if (kt + 64 < K) stage(kt + 64);
  }

  // Epilogue. C/D layout (m89-verified): col = lane&15, row = (lane>>4)*4 + j
  const int r0 = brow + wm * 64 + ((lane >> 4) << 2);
  const int c0 = bcol + wn * 64 + (lane & 15);
#pragma unroll
  for (int n = 0; n < 4; ++n) {
    const int col = c0 + n * 16;
    const float bval = bias ? bias[col] : 0.0f;
#pragma unroll
    for (int m = 0; m < 4; ++m) {
#pragma unroll
      for (int j = 0; j < 4; ++j) {
        const int r = r0 + m * 16 + j;
        float v = acc[m][n][j] * scale + bval;
        if (residual) v += residual[(long)r * ldc + col];
        if (OUTMODE == 0) {
          ((float*)Cv)[bz * sC + (long)r * ldc + col] = v;
        } else if (OUTMODE == 1) {
          ((bf16_t*)Cv)[bz * sC + (long)r * ldc + col] = (bf16_t)v;
        } else {
          const long bb = r >> 11;        // batch (SEQ=2048 rows per batch)
          const int ss = r & (SEQ - 1);
          ((bf16_t*)Cv)[bb * (long)(E_DIM * SEQ) + (long)col * SEQ + ss] = (bf16_t)v;
        }
      }
    }
  }
}

// ---------------- row softmax: f32 scores row (2048) -> bf16 P in-place ----------------
__global__ __launch_bounds__(256) void k_softmax(float* __restrict__ scores) {
  const long row = blockIdx.x;
  float* rp = scores + row * 2048;
  const int t = threadIdx.x;
  const float4 v0 = *(const float4*)(rp + t * 8);
  const float4 v1 = *(const float4*)(rp + t * 8 + 4);
  float x[8] = {v0.x, v0.y, v0.z, v0.w, v1.x, v1.y, v1.z, v1.w};
  float mx = x[0];
#pragma unroll
  for (int i = 1; i < 8; ++i) mx = fmaxf(mx, x[i]);
#pragma unroll
  for (int o = 32; o; o >>= 1) mx = fmaxf(mx, __shfl_xor(mx, o));
  __shared__ float redm[4], reds[4];
  const int lane = t & 63, w = t >> 6;
  if (lane == 0) redm[w] = mx;
  __syncthreads();
  mx = fmaxf(fmaxf(redm[0], redm[1]), fmaxf(redm[2], redm[3]));
  float p[8], s = 0.f;
#pragma unroll
  for (int i = 0; i < 8; ++i) { p[i] = __expf(x[i] - mx); s += p[i]; }
#pragma unroll
  for (int o = 32; o; o >>= 1) s += __shfl_xor(s, o);
  if (lane == 0) reds[w] = s;
  __syncthreads();  // also guarantees every lane's loads completed before in-place write
  const float inv = 1.0f / (reds[0] + reds[1] + reds[2] + reds[3]);
  bf16x8 o8;
#pragma unroll
  for (int i = 0; i < 8; ++i) o8[i] = (bf16_t)(p[i] * inv);
  *(bf16x8*)((bf16_t*)scores + row * 4096 + t * 8) = o8;  // P row stride = 4096 bf16
}

// ---------------- layernorm in-place on rows of 1024 f32 ----------------
__global__ __launch_bounds__(256) void k_layernorm(float* __restrict__ out,
                                                   const float* __restrict__ gamma,
                                                   const float* __restrict__ beta) {
  const long row = blockIdx.x;
  float* rp = out + row * 1024;
  const int t = threadIdx.x;
  const float4 v = *(const float4*)(rp + t * 4);
  float s = v.x + v.y + v.z + v.w;
#pragma unroll
  for (int o = 32; o; o >>= 1) s += __shfl_xor(s, o);
  __shared__ float red1[4], red2[4];
  const int lane = t & 63, w = t >> 6;
  if (lane == 0) red1[w] = s;
  __syncthreads();
  const float mu = (red1[0] + red1[1] + red1[2] + red1[3]) * (1.0f / 1024.0f);
  const float d0 = v.x - mu, d1 = v.y - mu, d2 = v.z - mu, d3 = v.w - mu;
  float ss = d0 * d0 + d1 * d1 + d2 * d2 + d3 * d3;
#pragma unroll
  for (int o = 32; o; o >>= 1) ss += __shfl_xor(ss, o);
  if (lane == 0) red2[w] = ss;
  __syncthreads();
  const float var = (red2[0] + red2[1] + red2[2] + red2[3]) * (1.0f / 1024.0f);
  const float rs = rsqrtf(var + 1e-6f);
  const float4 g = *(const float4*)(gamma + t * 4);
  const float4 b = *(const float4*)(beta + t * 4);
  float4 o;
  o.x = d0 * rs * g.x + b.x;
  o.y = d1 * rs * g.y + b.y;
  o.z = d2 * rs * g.z + b.z;
  o.w = d3 * rs * g.w + b.w;
  *(float4*)(rp + t * 4) = o;
}

extern "C" void kernel_launch(void* const* d_in, const int* in_sizes, int n_in,
                              void* d_out, int out_size, void* d_ws, size_t ws_size,
                              hipStream_t stream) {
  const float* query = (const float*)d_in[0];
  const float* key   = (const float*)d_in[1];
  const float* value = (const float*)d_in[2];
  const float* Wq = (const float*)d_in[3];
  const float* bq = (const float*)d_in[4];
  const float* Wk = (const float*)d_in[5];
  const float* bk = (const float*)d_in[6];
  const float* Wv = (const float*)d_in[7];
  const float* bv = (const float*)d_in[8];
  const float* Wo = (const float*)d_in[9];
  const float* bo = (const float*)d_in[10];
  const float* gamma = (const float*)d_in[11];
  const float* beta  = (const float*)d_in[12];
  float* out = (float*)d_out;

  char* ws = (char*)d_ws;
  const size_t XSZ  = (size_t)NBATCH * SEQ * E_DIM * 2;  // 16 MiB (bf16 activations)
  const size_t WSZ  = (size_t)E_DIM * E_DIM * 2;         // 2 MiB (bf16 weights)
  const size_t SCSZ = (size_t)NBATCH * SEQ * SEQ * 4;    // 64 MiB (f32 scores)

  // Layout (142.6 MB total). Scores overlay the X-bf16 region, which is dead
  // once the projections have run. P (bf16) is written in-place over scores.
  bf16_t* Xq  = (bf16_t*)(ws + 0);
  bf16_t* Xk  = (bf16_t*)(ws + XSZ);
  bf16_t* Xv  = (bf16_t*)(ws + 2 * XSZ);
  float*  SC  = (float*)(ws + 0);
  bf16_t* Wqb = (bf16_t*)(ws + SCSZ);
  bf16_t* Wkb = (bf16_t*)(ws + SCSZ + WSZ);
  bf16_t* Wvb = (bf16_t*)(ws + SCSZ + 2 * WSZ);
  bf16_t* Wob = (bf16_t*)(ws + SCSZ + 3 * WSZ);
  bf16_t* Qb  = (bf16_t*)(ws + SCSZ + 4 * WSZ);
  bf16_t* Kb  = (bf16_t*)(ws + SCSZ + 4 * WSZ + XSZ);
  bf16_t* Vt  = (bf16_t*)(ws + SCSZ + 4 * WSZ + 2 * XSZ);
  bf16_t* Ctx = (bf16_t*)(ws + SCSZ + 4 * WSZ + 3 * XSZ);

  const int NTOK = NBATCH * SEQ;  // 8192

  // 1) casts
  k_cast<<<dim3(NTOK * E_DIM / 2048), 256, 0, stream>>>(query, Xq);
  k_cast<<<dim3(NTOK * E_DIM / 2048), 256, 0, stream>>>(key, Xk);
  k_cast<<<dim3(NTOK * E_DIM / 2048), 256, 0, stream>>>(value, Xv);
  k_cast<<<dim3(E_DIM * E_DIM / 2048), 256, 0, stream>>>(Wq, Wqb);
  k_cast<<<dim3(E_DIM * E_DIM / 2048), 256, 0, stream>>>(Wk, Wkb);
  k_cast<<<dim3(E_DIM * E_DIM / 2048), 256, 0, stream>>>(Wv, Wvb);
  k_cast<<<dim3(E_DIM * E_DIM / 2048), 256, 0, stream>>>(Wo, Wob);

  // 2) projections: Q = Xq Wq^T + bq ; K = Xk Wk^T + bk ; Vt = (Xv Wv^T + bv)^T
  k_gemm<1><<<dim3(NTOK / 128, E_DIM / 128, 1), 256, 0, stream>>>(
      Xq, E_DIM, 0, Wqb, E_DIM, 0, Qb, E_DIM, 0, E_DIM, 1.0f, bq, nullptr);
  k_gemm<1><<<dim3(NTOK / 128, E_DIM / 128, 1), 256, 0, stream>>>(
      Xk, E_DIM, 0, Wkb, E_DIM, 0, Kb, E_DIM, 0, E_DIM, 1.0f, bk, nullptr);
  k_gemm<2><<<dim3(NTOK / 128, E_DIM / 128, 1), 256, 0, stream>>>(
      Xv, E_DIM, 0, Wvb, E_DIM, 0, Vt, 0, 0, E_DIM, 1.0f, bv, nullptr);

  // 3) scores = Q K^T / 32  (f32, per batch)
  k_gemm<0><<<dim3(SEQ / 128, SEQ / 128, NBATCH), 256, 0, stream>>>(
      Qb, E_DIM, (long)SEQ * E_DIM, Kb, E_DIM, (long)SEQ * E_DIM,
      SC, SEQ, (long)SEQ * SEQ, E_DIM, 0.03125f, nullptr, nullptr);

  // 4) softmax rows -> bf16 P in-place (row stride 4096 bf16)
  k_softmax<<<dim3(NTOK), 256, 0, stream>>>(SC);

  // 5) ctx = P @ V   (B-operand = Vt in [N][K] layout)
  k_gemm<1><<<dim3(SEQ / 128, E_DIM / 128, NBATCH), 256, 0, stream>>>(
      (const bf16_t*)SC, 2 * SEQ, (long)SEQ * 2 * SEQ, Vt, SEQ, (long)E_DIM * SEQ,
      Ctx, E_DIM, (long)SEQ * E_DIM, SEQ, 1.0f, nullptr, nullptr);

  // 6) out = ctx Wo^T + bo + residual(query)  (f32 into d_out)
  k_gemm<0><<<dim3(NTOK / 128, E_DIM / 128, 1), 256, 0, stream>>>(
      Ctx, E_DIM, 0, Wob, E_DIM, 0, out, E_DIM, 0, E_DIM, 1.0f, bo, query);

  // 7) layernorm in-place
  k_layernorm<<<dim3(NTOK), 256, 0, stream>>>(out, gamma, beta);
}

// Round 2
// 269.389 us; speedup vs baseline: 1.2174x; 1.2174x over previous
//
#include <hip/hip_runtime.h>
#include <hip/hip_bf16.h>

typedef __bf16 bf16_t;
typedef __bf16 bf16x4 __attribute__((ext_vector_type(4)));
typedef __bf16 bf16x8 __attribute__((ext_vector_type(8)));
typedef float f32x4 __attribute__((ext_vector_type(4)));

#define E_DIM 1024
#define SEQ   2048
#define NBATCH 4

#define BARR() __builtin_amdgcn_s_barrier()
#define LGKM0() asm volatile("s_waitcnt lgkmcnt(0)" ::: "memory")
#define VMC2() asm volatile("s_waitcnt vmcnt(2)" ::: "memory")
#define VMC3() asm volatile("s_waitcnt vmcnt(3)" ::: "memory")

// ---------------- cast f32 -> bf16 (vectorized, 8 elems/thread) ----------------
__global__ __launch_bounds__(256) void k_cast(const float* __restrict__ src,
                                              bf16_t* __restrict__ dst) {
  const int i = (blockIdx.x * 256 + threadIdx.x) * 8;
  const float4 a = *(const float4*)(src + i);
  const float4 b = *(const float4*)(src + i + 4);
  bf16x8 o;
  o[0] = (bf16_t)a.x; o[1] = (bf16_t)a.y; o[2] = (bf16_t)a.z; o[3] = (bf16_t)a.w;
  o[4] = (bf16_t)b.x; o[5] = (bf16_t)b.y; o[6] = (bf16_t)b.z; o[7] = (bf16_t)b.w;
  *(bf16x8*)(dst + i) = o;
}

// =================================================================================
// Phase-interleaved 256xBN GEMM, C = scale*(A @ B^T) + bias (+residual)
// A: [M][K] bf16 (lda), B: [N][K] bf16 (ldb), both K-contiguous.
// 8 waves (2M x 4N), per-wave tile 128 x BN/4. BK=64, double-buffered LDS.
// T2 XOR-swizzle (linear LDS dest + inverse-swizzled global source, swizzled read).
// T3/T4: per-phase chunk staging with counted vmcnt (never 0 in main loop).
// T5: setprio(1) around each 16-MFMA cluster. T1: XCD-swizzled 1D grid.
// OUTMODE 0: f32 out, 1: bf16 out, 2: bf16 transposed out (Vt[b][col][s]).
// =================================================================================
template <int BN, int OUTMODE>
__global__ __launch_bounds__(512, 2) void k_gemm2(
    const bf16_t* __restrict__ A, int lda, long sA,
    const bf16_t* __restrict__ B, int ldb, long sB,
    void* __restrict__ Cv, int ldc, long sC,
    int K, float scale, const float* __restrict__ bias,
    const float* __restrict__ residual, int GM, int GN) {
  extern __shared__ char smem[];
  constexpr int WVN = BN / 4;    // per-wave N width
  constexpr int NR  = BN / 64;   // n-fragments per wave
  constexpr int BNB = BN * 128;  // B tile bytes

  const int tid  = threadIdx.x;
  const int lane = tid & 63;
  const int wid  = tid >> 6;
  const int wm   = wid >> 2;  // 0..1
  const int wn   = wid & 3;   // 0..3

  // T1: XCD-swizzled workgroup decode (grid is always a multiple of 8)
  const int nwg  = gridDim.x;
  const int orig = blockIdx.x;
  const int wg   = (orig & 7) * (nwg >> 3) + (orig >> 3);
  const int zz   = wg / (GM * GN);
  const int rm   = wg - zz * (GM * GN);
  const int bm   = rm / GN;
  const int bn   = rm - bm * GN;
  const int brow = bm * 256;
  const int bcol = bn * BN;

  const bf16_t* Ab = A + (long)zz * sA;
  const bf16_t* Bb = B + (long)zz * sB;

  // Staging invariants. Each 8KB chunk = 64 rows x 128B; thread t covers
  // phys = t*16 within chunk -> row = t>>3, inverse-swizzled col below.
  const int colk = ((tid & 7) ^ ((tid >> 3) & 7)) << 3;  // element col in K-tile
  const bf16_t* Asrc = Ab + (long)(brow + (tid >> 3)) * lda + colk;
  const bf16_t* Bsrc = Bb + (long)(bcol + (tid >> 3)) * ldb + colk;
  const int ldsw = wid << 10;

  const int NT = K >> 6;

#define GLL(gaddr, ldsoff)                                                        \
  __builtin_amdgcn_global_load_lds(                                              \
      (const __attribute__((address_space(1))) void*)(gaddr),                    \
      (__attribute__((address_space(3))) void*)(smem + (ldsoff)), 16, 0, 0)

  auto stA = [&](int buf, int c, int tile) {
    GLL(Asrc + (long)(c * 64) * lda + tile * 64, buf * 32768 + c * 8192 + ldsw);
  };
  auto stB = [&](int buf, int c, int tile) {
    GLL(Bsrc + (long)(c * 64) * ldb + tile * 64, 65536 + buf * BNB + c * 8192 + ldsw);
  };

  f32x4 acc[8][NR];
#pragma unroll
  for (int m = 0; m < 8; ++m)
#pragma unroll
    for (int n = 0; n < NR; ++n) acc[m][n] = (f32x4){0.f, 0.f, 0.f, 0.f};

  bf16x8 af[4][2], bfr[2][2];
  const int arow = wm * 128 + (lane & 15);
  const int brl  = wn * WVN + (lane & 15);
  const int cbb  = (lane >> 4) << 4;  // byte col base within row; +kk*64

  auto ld_af = [&](int cur, int mq) {
#pragma unroll
    for (int m = 0; m < 4; ++m) {
      const int row = arow + mq * 64 + m * 16;
#pragma unroll
      for (int kk = 0; kk < 2; ++kk) {
        const int byt = cur * 32768 + row * 128 + ((kk * 64 + cbb) ^ ((row & 7) << 4));
        af[m][kk] = *(const bf16x8*)(smem + byt);
      }
    }
  };
  auto ld_bf = [&](int cur, int nq) {
#pragma unroll
    for (int n = 0; n < 2; ++n) {
      const int row = brl + nq * 32 + n * 16;
#pragma unroll
      for (int kk = 0; kk < 2; ++kk) {
        const int byt = 65536 + cur * BNB + row * 128 + ((kk * 64 + cbb) ^ ((row & 7) << 4));
        bfr[n][kk] = *(const bf16x8*)(smem + byt);
      }
    }
  };
  auto mma = [&](int mq, int nq) {
    __builtin_amdgcn_s_setprio(1);
#pragma unroll
    for (int kk = 0; kk < 2; ++kk)
#pragma unroll
      for (int m = 0; m < 4; ++m)
#pragma unroll
        for (int n = 0; n < 2; ++n)
          acc[mq * 4 + m][nq * 2 + n] = __builtin_amdgcn_mfma_f32_16x16x32_bf16(
              af[m][kk], bfr[n][kk], acc[mq * 4 + m][nq * 2 + n], 0, 0, 0);
    __builtin_amdgcn_s_setprio(0);
  };
  auto clampt = [&](int x) { return x < NT ? x : NT - 1; };

  // ---------------- prologue ----------------
  if constexpr (BN == 256) {
    stA(0, 0, 0); stA(0, 1, 0); stA(0, 2, 0); stA(0, 3, 0);
    stB(0, 0, 0); stB(0, 1, 0); stB(0, 2, 0); stB(0, 3, 0);
    const int t1 = clampt(1);
    stA(1, 0, t1); stA(1, 1, t1);  // A-half0(tile1): the "ph3 of t-1" stage
    VMC2(); BARR();
  } else {
    stA(0, 0, 0); stA(0, 1, 0); stA(0, 2, 0); stA(0, 3, 0);
    stB(0, 0, 0); stB(0, 1, 0);
    const int t1 = clampt(1);
    stA(1, 0, t1); stA(1, 2, t1); stB(1, 0, t1);  // the "ph1 of t-1" stage set
    VMC3(); BARR();
  }

  // ---------------- main loop (unrolled x2 so buffer index is literal) ----------
  auto iter = [&](int t, int cur) {
    const int t1 = clampt(t + 1);
    const int t2 = clampt(t + 2);
    if constexpr (BN == 256) {
      // ph0: A-half1(t+1) -> buf^1 (slots last read ph2 of t-1)
      stA(cur ^ 1, 2, t1); stA(cur ^ 1, 3, t1);
      ld_af(cur, 0); ld_bf(cur, 0);
      BARR(); LGKM0(); mma(0, 0); BARR();
      // ph1: B-half0(t+1) -> buf^1 (last read ph3 of t-1)
      stB(cur ^ 1, 0, t1); stB(cur ^ 1, 1, t1);
      ld_bf(cur, 1);
      BARR(); LGKM0(); mma(0, 1); BARR();
      // ph2: B-half1(t+1) -> buf^1
      stB(cur ^ 1, 2, t1); stB(cur ^ 1, 3, t1);
      ld_af(cur, 1); ld_bf(cur, 0);
      BARR(); LGKM0(); mma(1, 0); BARR();
      // ph3: A-half0(t+2) -> buf cur (A chunks 0/1 last read ph0/ph2 of t)
      stA(cur, 0, t2); stA(cur, 1, t2);
      ld_bf(cur, 1);
      BARR(); LGKM0(); mma(1, 1);
      VMC2();  // retire everything except the 2 loads just issued => tile t+1 landed
      BARR();
    } else {
      // ph0: {A-c1, A-c3, B-c1}(t+1) -> buf^1 (all last read ph1/ph0 of t-1)
      stA(cur ^ 1, 1, t1); stA(cur ^ 1, 3, t1); stB(cur ^ 1, 1, t1);
      ld_af(cur, 0); ld_bf(cur, 0);
      BARR(); LGKM0(); mma(0, 0); BARR();
      // ph1: {A-c0, A-c2, B-c0}(t+2) -> buf cur (all last read ph0 of t)
      stA(cur, 0, t2); stA(cur, 2, t2); stB(cur, 0, t2);
      ld_af(cur, 1);
      BARR(); LGKM0(); mma(1, 0);
      VMC3();  // retire through ph0's stages => tile t+1 fully landed
      BARR();
    }
  };

  for (int t = 0; t < NT; t += 2) {
    iter(t, 0);
    iter(t + 1, 1);
  }

  // ---------------- epilogue (C/D: col=lane&15, row=(lane>>4)*4+j) --------------
  const int r0 = brow + wm * 128 + ((lane >> 4) << 2);
  const int c0 = bcol + wn * WVN + (lane & 15);
#pragma unroll
  for (int n = 0; n < NR; ++n) {
    const int col = c0 + n * 16;
    const float bv = bias ? bias[col] : 0.0f;
#pragma unroll
    for (int m = 0; m < 8; ++m) {
      const int r = r0 + m * 16;
      if constexpr (OUTMODE == 2) {
        bf16x4 pk;
#pragma unroll
        for (int j = 0; j < 4; ++j) pk[j] = (bf16_t)(acc[m][n][j] * scale + bv);
        const long bb = (long)(r >> 11);
        const int ss = r & (SEQ - 1);
        *(bf16x4*)((bf16_t*)Cv + bb * ((long)E_DIM * SEQ) + (long)col * SEQ + ss) = pk;
      } else {
#pragma unroll
        for (int j = 0; j < 4; ++j) {
          float v = acc[m][n][j] * scale + bv;
          if (residual) v += residual[(long)(r + j) * ldc + col];
          const long idx = (long)zz * sC + (long)(r + j) * ldc + col;
          if constexpr (OUTMODE == 0) ((float*)Cv)[idx] = v;
          else ((bf16_t*)Cv)[idx] = (bf16_t)v;
        }
      }
    }
  }
#undef GLL
}

// ---------------- row softmax on bf16 scores (2048/row), bf16 P in place --------
__global__ __launch_bounds__(256) void k_softmax_bf(bf16_t* __restrict__ sc) {
  const long row = blockIdx.x;
  bf16_t* rp = sc + row * 2048;
  const int t = threadIdx.x;
  const bf16x8 v = *(const bf16x8*)(rp + t * 8);
  float x[8];
#pragma unroll
  for (int i = 0; i < 8; ++i) x[i] = (float)v[i];
  float mx = x[0];
#pragma unroll
  for (int i = 1; i < 8; ++i) mx = fmaxf(mx, x[i]);
#pragma unroll
  for (int o = 32; o; o >>= 1) mx = fmaxf(mx, __shfl_xor(mx, o));
  __shared__ float redm[4], reds[4];
  const int lane = t & 63, w = t >> 6;
  if (lane == 0) redm[w] = mx;
  __syncthreads();
  mx = fmaxf(fmaxf(redm[0], redm[1]), fmaxf(redm[2], redm[3]));
  float p[8], s = 0.f;
#pragma unroll
  for (int i = 0; i < 8; ++i) { p[i] = __expf(x[i] - mx); s += p[i]; }
#pragma unroll
  for (int o = 32; o; o >>= 1) s += __shfl_xor(s, o);
  if (lane == 0) reds[w] = s;
  __syncthreads();
  const float inv = 1.0f / (reds[0] + reds[1] + reds[2] + reds[3]);
  bf16x8 o8;
#pragma unroll
  for (int i = 0; i < 8; ++i) o8[i] = (bf16_t)(p[i] * inv);
  *(bf16x8*)(rp + t * 8) = o8;
}

// ---------------- layernorm in-place on rows of 1024 f32 ----------------
__global__ __launch_bounds__(256) void k_layernorm(float* __restrict__ out,
                                                   const float* __restrict__ gamma,
                                                   const float* __restrict__ beta) {
  const long row = blockIdx.x;
  float* rp = out + row * 1024;
  const int t = threadIdx.x;
  const float4 v = *(const float4*)(rp + t * 4);
  float s = v.x + v.y + v.z + v.w;
#pragma unroll
  for (int o = 32; o; o >>= 1) s += __shfl_xor(s, o);
  __shared__ float red1[4], red2[4];
  const int lane = t & 63, w = t >> 6;
  if (lane == 0) red1[w] = s;
  __syncthreads();
  const float mu = (red1[0] + red1[1] + red1[2] + red1[3]) * (1.0f / 1024.0f);
  const float d0 = v.x - mu, d1 = v.y - mu, d2 = v.z - mu, d3 = v.w - mu;
  float ss = d0 * d0 + d1 * d1 + d2 * d2 + d3 * d3;
#pragma unroll
  for (int o = 32; o; o >>= 1) ss += __shfl_xor(ss, o);
  if (lane == 0) red2[w] = ss;
  __syncthreads();
  const float var = (red2[0] + red2[1] + red2[2] + red2[3]) * (1.0f / 1024.0f);
  const float rs = rsqrtf(var + 1e-6f);
  const float4 g = *(const float4*)(gamma + t * 4);
  const float4 b = *(const float4*)(beta + t * 4);
  float4 o;
  o.x = d0 * rs * g.x + b.x;
  o.y = d1 * rs * g.y + b.y;
  o.z = d2 * rs * g.z + b.z;
  o.w = d3 * rs * g.w + b.w;
  *(float4*)(rp + t * 4) = o;
}

extern "C" void kernel_launch(void* const* d_in, const int* in_sizes, int n_in,
                              void* d_out, int out_size, void* d_ws, size_t ws_size,
                              hipStream_t stream) {
  const float* query = (const float*)d_in[0];
  const float* key   = (const float*)d_in[1];
  const float* value = (const float*)d_in[2];
  const float* Wq = (const float*)d_in[3];
  const float* bq = (const float*)d_in[4];
  const float* Wk = (const float*)d_in[5];
  const float* bk = (const float*)d_in[6];
  const float* Wv = (const float*)d_in[7];
  const float* bv = (const float*)d_in[8];
  const float* Wo = (const float*)d_in[9];
  const float* bo = (const float*)d_in[10];
  const float* gamma = (const float*)d_in[11];
  const float* beta  = (const float*)d_in[12];
  float* out = (float*)d_out;

  char* ws = (char*)d_ws;
  const size_t XSZ = (size_t)NBATCH * SEQ * E_DIM * 2;  // 16 MiB
  const size_t WSZ = (size_t)E_DIM * E_DIM * 2;         // 2 MiB
  const size_t B2  = 3 * XSZ;                           // 48 MiB boundary

  // bf16 scores (33.5 MB) overlay Xq/Xk/part-of-Xv; all X dead before scores run.
  bf16_t* Xq  = (bf16_t*)(ws + 0);
  bf16_t* Xk  = (bf16_t*)(ws + XSZ);
  bf16_t* Xv  = (bf16_t*)(ws + 2 * XSZ);
  bf16_t* SC  = (bf16_t*)(ws + 0);
  bf16_t* Wqb = (bf16_t*)(ws + B2);
  bf16_t* Wkb = (bf16_t*)(ws + B2 + WSZ);
  bf16_t* Wvb = (bf16_t*)(ws + B2 + 2 * WSZ);
  bf16_t* Wob = (bf16_t*)(ws + B2 + 3 * WSZ);
  bf16_t* Qb  = (bf16_t*)(ws + B2 + 4 * WSZ);
  bf16_t* Kb  = (bf16_t*)(ws + B2 + 4 * WSZ + XSZ);
  bf16_t* Vt  = (bf16_t*)(ws + B2 + 4 * WSZ + 2 * XSZ);
  bf16_t* Ctx = (bf16_t*)(ws + B2 + 4 * WSZ + 3 * XSZ);

  const int NTOK = NBATCH * SEQ;  // 8192
  const int SM128 = 98304, SM256 = 131072;

  // allow >64KB dynamic LDS (idempotent; not a stream op, graph-capture safe)
  static bool attr_done = false;
  hipFuncSetAttribute((const void*)k_gemm2<128, 0>, hipFuncAttributeMaxDynamicSharedMemorySize, SM128);
  hipFuncSetAttribute((const void*)k_gemm2<128, 1>, hipFuncAttributeMaxDynamicSharedMemorySize, SM128);
  hipFuncSetAttribute((const void*)k_gemm2<128, 2>, hipFuncAttributeMaxDynamicSharedMemorySize, SM128);
  hipFuncSetAttribute((const void*)k_gemm2<256, 1>, hipFuncAttributeMaxDynamicSharedMemorySize, SM256);
  (void)attr_done;

  // 1) casts
  k_cast<<<dim3(NTOK * E_DIM / 2048), 256, 0, stream>>>(query, Xq);
  k_cast<<<dim3(NTOK * E_DIM / 2048), 256, 0, stream>>>(key, Xk);
  k_cast<<<dim3(NTOK * E_DIM / 2048), 256, 0, stream>>>(value, Xv);
  k_cast<<<dim3(E_DIM * E_DIM / 2048), 256, 0, stream>>>(Wq, Wqb);
  k_cast<<<dim3(E_DIM * E_DIM / 2048), 256, 0, stream>>>(Wk, Wkb);
  k_cast<<<dim3(E_DIM * E_DIM / 2048), 256, 0, stream>>>(Wv, Wvb);
  k_cast<<<dim3(E_DIM * E_DIM / 2048), 256, 0, stream>>>(Wo, Wob);

  // 2) projections (BN=128: grid 32x8 = 256 wg, full GPU)
  k_gemm2<128, 1><<<256, 512, SM128, stream>>>(
      Xq, E_DIM, 0, Wqb, E_DIM, 0, Qb, E_DIM, 0, E_DIM, 1.0f, bq, nullptr, 32, 8);
  k_gemm2<128, 1><<<256, 512, SM128, stream>>>(
      Xk, E_DIM, 0, Wkb, E_DIM, 0, Kb, E_DIM, 0, E_DIM, 1.0f, bk, nullptr, 32, 8);
  k_gemm2<128, 2><<<256, 512, SM128, stream>>>(
      Xv, E_DIM, 0, Wvb, E_DIM, 0, Vt, 0, 0, E_DIM, 1.0f, bv, nullptr, 32, 8);

  // 3) scores = Q K^T / 32 -> bf16 (BN=256: grid 8x8x4 = 256 wg)
  k_gemm2<256, 1><<<256, 512, SM256, stream>>>(
      Qb, E_DIM, (long)SEQ * E_DIM, Kb, E_DIM, (long)SEQ * E_DIM,
      SC, SEQ, (long)SEQ * SEQ, E_DIM, 0.03125f, nullptr, nullptr, 8, 8);

  // 4) softmax rows -> bf16 P in place
  k_softmax_bf<<<dim3(NTOK), 256, 0, stream>>>(SC);

  // 5) ctx = P @ V (B = Vt in [N][K] layout; BN=128: grid 8x8x4 = 256 wg)
  k_gemm2<128, 1><<<256, 512, SM128, stream>>>(
      SC, SEQ, (long)SEQ * SEQ, Vt, SEQ, (long)E_DIM * SEQ,
      Ctx, E_DIM, (long)SEQ * E_DIM, SEQ, 1.0f, nullptr, nullptr, 8, 8);

  // 6) out = ctx Wo^T + bo + residual (f32 into d_out)
  k_gemm2<128, 0><<<256, 512, SM128, stream>>>(
      Ctx, E_DIM, 0, Wob, E_DIM, 0, out, E_DIM, 0, E_DIM, 1.0f, bo, query, 32, 8);

  // 7) layernorm in-place
  k_layernorm<<<dim3(NTOK), 256, 0, stream>>>(out, gamma, beta);
}